// Round 8
// baseline (370.648 us; speedup 1.0000x reference)
//
#include <hip/hip_runtime.h>
#include <math.h>

#define BB 512
#define NN 512
#define DD 128
#define REP 32   // DIAGNOSTIC: amplify streaming phase x32 to surface the
                 // kernel's true dispatch duration in the rocprof top-5
                 // (harness fills are 75us; un-amplified kernel is hidden).
                 // Output remains bit-identical to R5: only the final rep's
                 // accumulators are used and its laundered bias == bg.

// One block per graph b, 512 threads = 16 row-groups x 32 lanes (R5 structure,
// best so far at 24.8us). Zero inter-block communication.
__global__ __launch_bounds__(512) void k_graph(
    const float* __restrict__ h,
    const int*   __restrict__ ns,
    const float* __restrict__ W_g,
    const float* __restrict__ b_g,
    const float* __restrict__ W_f,
    const float* __restrict__ b_f,
    float*       __restrict__ out)
{
    const int b    = blockIdx.x;
    const int tid  = threadIdx.x;
    const int grp  = tid >> 5;       // 0..15
    const int lane = tid & 31;

    const int end = ns[b];           // 1..512 valid rows

    __shared__ float lds_s[16 * 128];
    __shared__ float lds_t[16];
    __shared__ float red[2];

    const float4 wg = ((const float4*)W_g)[lane];
    const float  bg = b_g[0];
    const float4* hb = (const float4*)(h + (size_t)b * NN * DD);  // row r -> hb[r*32+lane]

    float4 acc  = make_float4(0.f, 0.f, 0.f, 0.f);
    float  tacc = 0.f;

    #pragma unroll 1
    for (int rep = 0; rep < REP; ++rep) {
        // launder the bias: compiler can't prove reps compute the same value,
        // so the whole streaming pass must be re-executed each rep (no CSE).
        float bgr = bg;
        asm volatile("" : "+v"(bgr));

        acc  = make_float4(0.f, 0.f, 0.f, 0.f);
        tacc = 0.f;

        int n = grp;
        for (; n + 48 < end; n += 64) {          // 4 rows in flight per group
            const float4 v0 = hb[(size_t)(n     ) * 32 + lane];
            const float4 v1 = hb[(size_t)(n + 16) * 32 + lane];
            const float4 v2 = hb[(size_t)(n + 32) * 32 + lane];
            const float4 v3 = hb[(size_t)(n + 48) * 32 + lane];

            float d0 = v0.x * wg.x + v0.y * wg.y + v0.z * wg.z + v0.w * wg.w;
            float d1 = v1.x * wg.x + v1.y * wg.y + v1.z * wg.z + v1.w * wg.w;
            float d2 = v2.x * wg.x + v2.y * wg.y + v2.z * wg.z + v2.w * wg.w;
            float d3 = v3.x * wg.x + v3.y * wg.y + v3.z * wg.z + v3.w * wg.w;
            #pragma unroll
            for (int m = 1; m <= 16; m <<= 1) {
                d0 += __shfl_xor(d0, m);
                d1 += __shfl_xor(d1, m);
                d2 += __shfl_xor(d2, m);
                d3 += __shfl_xor(d3, m);
            }
            const float g0 = 1.f / (1.f + expf(-(d0 + bgr)));
            const float g1 = 1.f / (1.f + expf(-(d1 + bgr)));
            const float g2 = 1.f / (1.f + expf(-(d2 + bgr)));
            const float g3 = 1.f / (1.f + expf(-(d3 + bgr)));

            acc.x += g0 * v0.x + g1 * v1.x + g2 * v2.x + g3 * v3.x;
            acc.y += g0 * v0.y + g1 * v1.y + g2 * v2.y + g3 * v3.y;
            acc.z += g0 * v0.z + g1 * v1.z + g2 * v2.z + g3 * v3.z;
            acc.w += g0 * v0.w + g1 * v1.w + g2 * v2.w + g3 * v3.w;
            tacc  += g0 + g1 + g2 + g3;
        }
        for (; n < end; n += 16) {               // remainder rows
            const float4 v = hb[(size_t)n * 32 + lane];
            float d = v.x * wg.x + v.y * wg.y + v.z * wg.z + v.w * wg.w;
            #pragma unroll
            for (int m = 1; m <= 16; m <<= 1) d += __shfl_xor(d, m);
            const float g = 1.f / (1.f + expf(-(d + bgr)));
            acc.x += g * v.x;
            acc.y += g * v.y;
            acc.z += g * v.z;
            acc.w += g * v.w;
            tacc  += g;
        }

        // sink: keeps every rep's results live (no DCE of loads/compute)
        asm volatile("" :: "v"(acc.x), "v"(acc.y), "v"(acc.z), "v"(acc.w), "v"(tacc));
    }

    // cross-group reduction via LDS (uses final rep's acc/tacc == true values)
    ((float4*)lds_s)[grp * 32 + lane] = acc;
    if (lane == 0) lds_t[grp] = tacc;
    __syncthreads();

    // ---- finalize within the block ----
    float s = 0.f, t = 0.f;
    if (tid < 128) {
        #pragma unroll
        for (int g2 = 0; g2 < 16; ++g2) s += lds_s[g2 * 128 + tid];
        #pragma unroll
        for (int g2 = 0; g2 < 16; ++g2) t += lds_t[g2];              // broadcast
    }
    __syncthreads();                          // all reads of lds_s done before overwrite
    if (tid < 128) lds_s[tid] = s;            // compact s into first 128 slots
    __syncthreads();                          // s visible to waves 0-1

    float hg = 0.f;
    if (tid < 128) {
        hg = t * b_f[tid];
        const float4* wrow = (const float4*)(W_f + (size_t)tid * DD);
        const float4* sv   = (const float4*)lds_s;
        #pragma unroll 8
        for (int k = 0; k < 32; ++k) {
            const float4 w  = wrow[k];
            const float4 sk = sv[k];          // LDS broadcast, conflict-free
            hg += w.x * sk.x + w.y * sk.y + w.z * sk.z + w.w * sk.w;
        }
        float sq = hg * hg;
        sq += __shfl_xor(sq, 1);
        sq += __shfl_xor(sq, 2);
        sq += __shfl_xor(sq, 4);
        sq += __shfl_xor(sq, 8);
        sq += __shfl_xor(sq, 16);
        sq += __shfl_xor(sq, 32);
        if ((tid & 63) == 0) red[tid >> 6] = sq;
    }
    __syncthreads();
    if (tid < 128) {
        const float norm = sqrtf(red[0] + red[1]);
        out[(size_t)b * DD + tid] = hg / fmaxf(norm, 1e-12f);
    }
}

extern "C" void kernel_launch(void* const* d_in, const int* in_sizes, int n_in,
                              void* d_out, int out_size, void* d_ws, size_t ws_size,
                              hipStream_t stream) {
    const float* h   = (const float*)d_in[0];
    const int*   ns  = (const int*)  d_in[1];
    const float* W_f = (const float*)d_in[2];
    const float* b_f = (const float*)d_in[3];
    const float* W_g = (const float*)d_in[4];
    const float* b_g = (const float*)d_in[5];
    float* out = (float*)d_out;

    k_graph<<<BB, 512, 0, stream>>>(h, ns, W_g, b_g, W_f, b_f, out);
}

// Round 9
// 21.680 us; speedup vs baseline: 17.0963x; 17.0963x over previous
//
#include <hip/hip_runtime.h>
#include <math.h>

#define BB 512
#define NN 512
#define DD 128

// One block per graph b, 512 threads = 8 waves. 8-lane-per-row layout:
// lane l covers row (l>>3) of the wave's 8-row slice, elements
// d = (l&7)*4 + c*32 + {0..3}, c=0..3 (16 floats/lane/row).
// Per 8 rows: 4 loads + 16 dot-FMA + 3 shfl + ~5 sigmoid + 16 acc-FMA
// (R5's layout paid 20 shfl + ~16-op libm sigmoid per 4 rows -> VALU/DS
// bound at 45% VALUBusy, stream ~11.8us measured by R8 REP=32 diagnostic).
// Zero inter-block communication (R4 fences +280us, R6 agent atomics +12us).
__global__ __launch_bounds__(512) void k_graph(
    const float* __restrict__ h,
    const int*   __restrict__ ns,
    const float* __restrict__ W_g,
    const float* __restrict__ b_g,
    const float* __restrict__ W_f,
    const float* __restrict__ b_f,
    float*       __restrict__ out)
{
    const int b    = blockIdx.x;
    const int tid  = threadIdx.x;
    const int wv   = tid >> 6;        // wave 0..7
    const int lane = tid & 63;
    const int sub  = lane & 7;        // element-slice within row
    const int rowg = lane >> 3;       // which of the wave's 8 rows

    const int end = ns[b];            // 1..512 valid rows

    __shared__ float lds_s[8 * 128];
    __shared__ float lds_t[8];
    __shared__ float red[2];

    // W_g fragment: d = (c*8+sub)*4 .. +3  for c=0..3
    const float4 wg0 = ((const float4*)W_g)[ 0 + sub];
    const float4 wg1 = ((const float4*)W_g)[ 8 + sub];
    const float4 wg2 = ((const float4*)W_g)[16 + sub];
    const float4 wg3 = ((const float4*)W_g)[24 + sub];
    const float  bg  = b_g[0];

    const float4* hb = (const float4*)(h + (size_t)b * NN * DD);  // row r -> hb[r*32 + idx]

    float4 a0 = make_float4(0.f,0.f,0.f,0.f);
    float4 a1 = make_float4(0.f,0.f,0.f,0.f);
    float4 a2 = make_float4(0.f,0.f,0.f,0.f);
    float4 a3 = make_float4(0.f,0.f,0.f,0.f);
    float  tacc = 0.f;

    for (int n0 = wv * 8; n0 < end; n0 += 64) {
        int r = n0 + rowg;
        const float valid = (r < end) ? 1.f : 0.f;   // predicated tail
        r = (r < end) ? r : (end - 1);               // clamped: always a legal load
        const float4* rp = hb + (size_t)r * 32 + sub;
        const float4 v0 = rp[ 0];                    // c=0 (offset   0)
        const float4 v1 = rp[ 8];                    // c=1 (offset 128B)
        const float4 v2 = rp[16];                    // c=2
        const float4 v3 = rp[24];                    // c=3

        float d = v0.x*wg0.x + v0.y*wg0.y + v0.z*wg0.z + v0.w*wg0.w
                + v1.x*wg1.x + v1.y*wg1.y + v1.z*wg1.z + v1.w*wg1.w
                + v2.x*wg2.x + v2.y*wg2.y + v2.z*wg2.z + v2.w*wg2.w
                + v3.x*wg3.x + v3.y*wg3.y + v3.z*wg3.z + v3.w*wg3.w;
        d += __shfl_xor(d, 1);                       // reduce across the 8-lane group
        d += __shfl_xor(d, 2);
        d += __shfl_xor(d, 4);

        // fast sigmoid: 1/(1 + 2^(-(d+bg)*log2e)) via v_exp/v_rcp (~1 ulp each)
        const float texp = (d + bg) * -1.44269504f;
        float e;
        asm("v_exp_f32 %0, %1" : "=v"(e) : "v"(texp));
        const float ep1 = e + 1.f;
        float gr;
        asm("v_rcp_f32 %0, %1" : "=v"(gr) : "v"(ep1));
        const float g = valid * gr;

        a0.x += g*v0.x; a0.y += g*v0.y; a0.z += g*v0.z; a0.w += g*v0.w;
        a1.x += g*v1.x; a1.y += g*v1.y; a1.z += g*v1.z; a1.w += g*v1.w;
        a2.x += g*v2.x; a2.y += g*v2.y; a2.z += g*v2.z; a2.w += g*v2.w;
        a3.x += g*v3.x; a3.y += g*v3.y; a3.z += g*v3.z; a3.w += g*v3.w;
        tacc += g;    // identical across the 8 lanes of a row-group
    }

    // reduce across the wave's 8 row-groups (lane bits 3..5). tacc: bits 0-2
    // NOT reduced, so the 8 in-group copies aren't multiply-counted.
    #pragma unroll
    for (int m = 8; m <= 32; m <<= 1) {
        a0.x += __shfl_xor(a0.x, m); a0.y += __shfl_xor(a0.y, m);
        a0.z += __shfl_xor(a0.z, m); a0.w += __shfl_xor(a0.w, m);
        a1.x += __shfl_xor(a1.x, m); a1.y += __shfl_xor(a1.y, m);
        a1.z += __shfl_xor(a1.z, m); a1.w += __shfl_xor(a1.w, m);
        a2.x += __shfl_xor(a2.x, m); a2.y += __shfl_xor(a2.y, m);
        a2.z += __shfl_xor(a2.z, m); a2.w += __shfl_xor(a2.w, m);
        a3.x += __shfl_xor(a3.x, m); a3.y += __shfl_xor(a3.y, m);
        a3.z += __shfl_xor(a3.z, m); a3.w += __shfl_xor(a3.w, m);
        tacc += __shfl_xor(tacc, m);
    }

    if (rowg == 0) {                   // lanes 0..7 of each wave hold the wave totals
        float4* dst = (float4*)lds_s + wv * 32;
        dst[ 0 + sub] = a0;            // d = sub*4 + c*32: matches lds_s[wv][d]
        dst[ 8 + sub] = a1;
        dst[16 + sub] = a2;
        dst[24 + sub] = a3;
        if (sub == 0) lds_t[wv] = tacc;
    }
    __syncthreads();

    // ---- finalize within the block ----
    float s = 0.f, t = 0.f;
    if (tid < 128) {
        #pragma unroll
        for (int g2 = 0; g2 < 8; ++g2) s += lds_s[g2 * 128 + tid];
        #pragma unroll
        for (int g2 = 0; g2 < 8; ++g2) t += lds_t[g2];              // broadcast
    }
    __syncthreads();                          // all reads of lds_s done before overwrite
    if (tid < 128) lds_s[tid] = s;            // compact s into first 128 slots
    __syncthreads();                          // s visible to waves 0-1

    float hg = 0.f;
    if (tid < 128) {
        hg = t * b_f[tid];
        const float4* wrow = (const float4*)(W_f + (size_t)tid * DD);
        const float4* sv   = (const float4*)lds_s;
        #pragma unroll 8
        for (int k = 0; k < 32; ++k) {
            const float4 w  = wrow[k];
            const float4 sk = sv[k];          // LDS broadcast, conflict-free
            hg += w.x * sk.x + w.y * sk.y + w.z * sk.z + w.w * sk.w;
        }
        float sq = hg * hg;
        sq += __shfl_xor(sq, 1);
        sq += __shfl_xor(sq, 2);
        sq += __shfl_xor(sq, 4);
        sq += __shfl_xor(sq, 8);
        sq += __shfl_xor(sq, 16);
        sq += __shfl_xor(sq, 32);
        if ((tid & 63) == 0) red[tid >> 6] = sq;
    }
    __syncthreads();
    if (tid < 128) {
        const float norm = sqrtf(red[0] + red[1]);
        out[(size_t)b * DD + tid] = hg / fmaxf(norm, 1e-12f);
    }
}

extern "C" void kernel_launch(void* const* d_in, const int* in_sizes, int n_in,
                              void* d_out, int out_size, void* d_ws, size_t ws_size,
                              hipStream_t stream) {
    const float* h   = (const float*)d_in[0];
    const int*   ns  = (const int*)  d_in[1];
    const float* W_f = (const float*)d_in[2];
    const float* b_f = (const float*)d_in[3];
    const float* W_g = (const float*)d_in[4];
    const float* b_g = (const float*)d_in[5];
    float* out = (float*)d_out;

    k_graph<<<BB, 512, 0, stream>>>(h, ns, W_g, b_g, W_f, b_f, out);
}